// Round 14
// baseline (923.428 us; speedup 1.0000x reference)
//
#include <hip/hip_runtime.h>
#include <hip/hip_bf16.h>
#include <math.h>

#define NN 100000
#define NNP 100096          // padded to 1564*64
#define NE 300000
#define HID 128
#define EMB 64
#define NG 4096
#define DEG_CAP 32
#define XS 512              // X row stride in elements

typedef __bf16 bf16x8 __attribute__((ext_vector_type(8)));
typedef float  f32x16 __attribute__((ext_vector_type(16)));
typedef short  short8 __attribute__((ext_vector_type(8)));

typedef const __attribute__((address_space(1))) unsigned int* gas_u32;
typedef __attribute__((address_space(3))) unsigned int* las_u32;

__device__ __forceinline__ void gload16(const void* g, void* l) {
    __builtin_amdgcn_global_load_lds((gas_u32)g, (las_u32)l, 16, 0, 0);
}

__device__ __forceinline__ float bf2f(unsigned short u) {
    unsigned int x = ((unsigned int)u) << 16;
    return __builtin_bit_cast(float, x);
}
__device__ __forceinline__ unsigned short f2bf(float f) {
    unsigned int x = __builtin_bit_cast(unsigned int, f);
    unsigned int r = x + 0x7fff + ((x >> 16) & 1);
    return (unsigned short)(r >> 16);
}
__device__ __forceinline__ float sigm(float x) { return 1.f / (1.f + __expf(-x)); }

#define MFMA(A, B, C) __builtin_amdgcn_mfma_f32_32x32x16_bf16( \
    __builtin_bit_cast(bf16x8, A), __builtin_bit_cast(bf16x8, B), C, 0, 0, 0)

// ---------------------------------------------------------------------------
// h init: node_features f32 -> Y bf16 [NNP][128]; pad rows zeroed.
// ---------------------------------------------------------------------------
__global__ __launch_bounds__(256) void k_init(const float* __restrict__ nf,
                                              unsigned short* __restrict__ Y) {
    int id = blockIdx.x * 256 + threadIdx.x;   // NNP*HID
    int n = id >> 7, c = id & 127;
    Y[(long)n * HID + c] = (n < NN) ? f2bf(nf[(long)n * HID + c]) : (unsigned short)0;
}

// ---------------------------------------------------------------------------
// CSR build (deg true counts; csr capped at DEG_CAP)
// ---------------------------------------------------------------------------
__global__ __launch_bounds__(256) void k_build_csr(const int* __restrict__ ei,
                                                   int* __restrict__ deg,
                                                   int* __restrict__ csr) {
    int id = blockIdx.x * 256 + threadIdx.x;
    if (id >= 3 * NE) return;
    int t = id / NE;
    int i = id - t * NE;
    int src = ei[(t * 2 + 0) * NE + i];
    int dst = ei[(t * 2 + 1) * NE + i];
    int p = atomicAdd(&deg[t * NN + dst], 1);
    if (p < DEG_CAP) csr[((long)t * NN + dst) * DEG_CAP + p] = src;
}

__global__ __launch_bounds__(256) void k_pack_deg(const int* __restrict__ deg,
                                                  int4* __restrict__ degp) {
    int n = blockIdx.x * 256 + threadIdx.x;
    if (n >= NNP) return;
    int4 v; v.x = 0; v.y = 0; v.z = 0; v.w = 0;
    if (n < NN) { v.x = deg[n]; v.y = deg[NN + n]; v.z = deg[2 * NN + n]; }
    degp[n] = v;
}

// ---------------------------------------------------------------------------
// Bf: FRAGMENT-ORDERED weights. n' = c*4 + sec (sec-minor). For MFMA
// 32x32x16 B-operand, lane = kg*32 + nl supplies B[n' = nb*32+nl]
// [k = k16*16 + kg*8 + e]. Fragment (nb,k16) = contiguous 1KB.
// K layout: k<384 -> A_cat (Wm @ Wih_sec^T), k>=384 -> h (Whh_sec).
// ---------------------------------------------------------------------------
__global__ __launch_bounds__(512) void k_build_w(const float* __restrict__ Wmsg,
                                                 const float* __restrict__ Wih,
                                                 const float* __restrict__ Whh,
                                                 unsigned short* __restrict__ Bf) {
    int np = blockIdx.x;       // 0..511 permuted col
    int k = threadIdx.x;       // 0..511
    int c = np >> 2, sec = np & 3;
    float v = 0.f;
    if (k < 384) {
        if (sec < 3) {
            int t = k >> 7, kk = k & 127;
            const float* wm = Wmsg + ((long)t * HID + kk) * HID;
            const float* wi = Wih + (long)(sec * HID + c) * HID;
            float s = 0.f;
            for (int j = 0; j < HID; j++) s += wm[j] * wi[j];
            v = s;
        }
    } else {
        int kk = k - 384;
        if (sec == 0)      v = Whh[(long)c * HID + kk];
        else if (sec == 1) v = Whh[(long)(HID + c) * HID + kk];
        else if (sec == 3) v = Whh[(long)(2 * HID + c) * HID + kk];
    }
    int nb = np >> 5, nl = np & 31;
    int k16 = k >> 4, kgg = (k >> 3) & 1, e = k & 7;
    Bf[((((nb * 32 + k16) * 2 + kgg) * 32 + nl) << 3) + e] = f2bf(v);
}

__global__ __launch_bounds__(512) void k_build_bias(const float* __restrict__ bih,
                                                    const float* __restrict__ bhh,
                                                    const float* __restrict__ bmsg,
                                                    const float* __restrict__ Wih,
                                                    float* __restrict__ bbig,
                                                    float* __restrict__ Bdeg) {
    int np = threadIdx.x;      // 0..511 permuted
    int c = np >> 2, sec = np & 3;
    float b;
    if (sec == 0)      b = bih[c] + bhh[c];
    else if (sec == 1) b = bih[HID + c] + bhh[HID + c];
    else if (sec == 2) b = bih[2 * HID + c];
    else               b = bhh[2 * HID + c];
    bbig[np] = b;
    for (int t = 0; t < 3; t++) {
        float s = 0.f;
        if (sec < 3) {
            const float* wi = Wih + (long)(sec * HID + c) * HID;
            const float* bm = bmsg + t * HID;
            for (int j = 0; j < HID; j++) s += bm[j] * wi[j];
        }
        Bdeg[t * 512 + np] = s;
    }
}

// ---------------------------------------------------------------------------
// Aggregate: one WAVE per node, gather from compact Y [n][128], write A_cat
// into X cols 0..383 AND copy h (Y row) into X cols 384..511.
// ---------------------------------------------------------------------------
__global__ __launch_bounds__(256) void k_agg(const unsigned short* __restrict__ Y,
                                             unsigned short* __restrict__ X,
                                             const int* __restrict__ deg,
                                             const int* __restrict__ csr) {
    const int lane = threadIdx.x & 63;
    const long n = (long)blockIdx.x * 4 + (threadIdx.x >> 6);
    const int g = lane >> 4;
    const int c16 = lane & 15;
    const int l31 = lane & 31;

    int d[3], il[3];
#pragma unroll
    for (int t = 0; t < 3; t++) {
        int dt = deg[t * NN + n];
        d[t] = dt > DEG_CAP ? DEG_CAP : dt;
        il[t] = csr[((long)t * NN + n) * DEG_CAP + l31];
    }
#pragma unroll
    for (int t = 0; t < 3; t++) {
        float acc[8] = {0.f, 0.f, 0.f, 0.f, 0.f, 0.f, 0.f, 0.f};
        int rounds = (d[t] + 3) >> 2;
        for (int r = 0; r < rounds; r++) {
            int j = r * 4 + g;
            int idx = __shfl(il[t], j & 31);
            if (j < d[t]) {
                short8 v = *(const short8*)(Y + (long)idx * HID + c16 * 8);
#pragma unroll
                for (int q = 0; q < 8; q++) acc[q] += bf2f((unsigned short)v[q]);
            }
        }
#pragma unroll
        for (int q = 0; q < 8; q++) {
            acc[q] += __shfl_xor(acc[q], 16);
            acc[q] += __shfl_xor(acc[q], 32);
        }
        if (g == 0) {
            short8 o;
#pragma unroll
            for (int q = 0; q < 8; q++) o[q] = (short)f2bf(acc[q]);
            *(short8*)(X + n * XS + t * HID + c16 * 8) = o;
        }
    }
    if (g == 1) {   // h copy: Y row -> X cols 384..511
        short8 v = *(const short8*)(Y + n * HID + c16 * 8);
        *(short8*)(X + n * XS + 384 + c16 * 8) = v;
    }
}

// ---------------------------------------------------------------------------
// Fused GRU step (R12 verbatim — best measured config, 121us/dispatch).
// ---------------------------------------------------------------------------
__global__ __launch_bounds__(512, 4) void k_gru_mfma(
        const unsigned short* __restrict__ X,
        const unsigned short* __restrict__ Y,
        unsigned short* __restrict__ Yw,
        const unsigned short* __restrict__ Bf,
        const float* __restrict__ bbig, const float* __restrict__ Bdeg,
        const int4* __restrict__ degp) {
    __shared__ char lds[66048];

    const int tid = threadIdx.x;
    const int lane = tid & 63;
    const int wv = tid >> 6;        // 0..7 = N slot (64 cols each)
    const int r31 = lane & 31;
    const int kg = lane >> 5;
    const long row0 = (long)blockIdx.x * 64;

    f32x16 acc[2][2];
#pragma unroll
    for (int i = 0; i < 2; i++)
#pragma unroll
        for (int j = 0; j < 2; j++) acc[i][j] = (f32x16)(0.0f);

    const char* pAl = (const char*)X + (row0 + r31) * 1024 + kg * 16;
#define STAGE_A(HALF)                                                           \
    {                                                                           \
        _Pragma("unroll")                                                       \
        for (int jj = 0; jj < 4; jj++) {                                        \
            const int f = wv * 4 + jj;                                          \
            gload16(pAl + (f & 1) * 32768 + ((HALF) * 16 + (f >> 1)) * 32,      \
                    lds + f * 1024);                                            \
        }                                                                       \
    }

    const unsigned short* pB0 = Bf + (wv * 2 + 0) * 16384 + lane * 8;
    const unsigned short* pB1 = Bf + (wv * 2 + 1) * 16384 + lane * 8;

    STAGE_A(0);
    __syncthreads();

#pragma unroll
    for (int k16l = 0; k16l < 16; k16l++) {
        short8 a0 = *(const short8*)(lds + (k16l * 2 + 0) * 1024 + lane * 16);
        short8 a1 = *(const short8*)(lds + (k16l * 2 + 1) * 1024 + lane * 16);
        short8 b0 = *(const short8*)(pB0 + k16l * 512);
        short8 b1 = *(const short8*)(pB1 + k16l * 512);
        acc[0][0] = MFMA(a0, b0, acc[0][0]);
        acc[0][1] = MFMA(a0, b1, acc[0][1]);
        acc[1][0] = MFMA(a1, b0, acc[1][0]);
        acc[1][1] = MFMA(a1, b1, acc[1][1]);
    }

    __syncthreads();
    STAGE_A(1);
    __syncthreads();
#undef STAGE_A

#pragma unroll
    for (int k16l = 0; k16l < 16; k16l++) {
        const int k16g = 16 + k16l;
        short8 a0 = *(const short8*)(lds + (k16l * 2 + 0) * 1024 + lane * 16);
        short8 a1 = *(const short8*)(lds + (k16l * 2 + 1) * 1024 + lane * 16);
        short8 b0 = *(const short8*)(pB0 + k16g * 512);
        short8 b1 = *(const short8*)(pB1 + k16g * 512);
        acc[0][0] = MFMA(a0, b0, acc[0][0]);
        acc[0][1] = MFMA(a0, b1, acc[0][1]);
        acc[1][0] = MFMA(a1, b0, acc[1][0]);
        acc[1][1] = MFMA(a1, b1, acc[1][1]);
    }

    // ---- epilogue v2: 2 halves; EX = [32 rows][516] f32 ----
    float* EX = (float*)lds;
    const int ch = tid & 127;
    const int r5b = tid >> 7;
    const float4 bb = *(const float4*)(bbig + ch * 4);
    const float4 q0v = *(const float4*)(Bdeg + ch * 4);
    const float4 q1v = *(const float4*)(Bdeg + 512 + ch * 4);
    const float4 q2v = *(const float4*)(Bdeg + 1024 + ch * 4);

#pragma unroll
    for (int half = 0; half < 2; half++) {
        __syncthreads();
#pragma unroll
        for (int ct = 0; ct < 2; ct++) {
            const int col = wv * 64 + ct * 32 + r31;
#pragma unroll
            for (int reg = 0; reg < 16; reg++) {
                int r5 = (reg & 3) + 8 * (reg >> 2) + 4 * kg;
                EX[r5 * 516 + col] = half ? acc[1][ct][reg] : acc[0][ct][reg];
            }
        }
        __syncthreads();
#pragma unroll
        for (int i = 0; i < 8; i++) {
            const int r5 = r5b + 4 * i;
            long grow = row0 + half * 32 + r5;
            int4 dg = degp[grow];
            float dgx = (float)dg.x, dgy = (float)dg.y, dgz = (float)dg.z;
            float4 v = *(const float4*)(EX + r5 * 516 + ch * 4);
            float Sr = v.x + bb.x + dgx * q0v.x + dgy * q1v.x + dgz * q2v.x;
            float Sz = v.y + bb.y + dgx * q0v.y + dgy * q1v.y + dgz * q2v.y;
            float In = v.z + bb.z + dgx * q0v.z + dgy * q1v.z + dgz * q2v.z;
            float Hn = v.w + bb.w;
            float rr = sigm(Sr);
            float zz = sigm(Sz);
            float tt = In + rr * Hn;
            float ee = __expf(2.f * tt);
            float nn = 1.f - 2.f / (ee + 1.f);
            float hv = (1.f - zz) * nn + zz * bf2f(Y[grow * HID + ch]);
            Yw[grow * HID + ch] = f2bf(hv);
        }
    }
}

// ---------------------------------------------------------------------------
// ABLATION kernels (diagnostic only; write to scratch Ys, never d_out).
// V0 = full GEMM core (stage + A ds_read + B loads + MFMA) — control.
// V1 = B loads removed (frag-0 reuse)   — isolates B-load latency.
// V2 = A ds_reads removed (B kept)      — isolates LDS-read latency.
// V3 = MFMA + stage only                — floor.
// Same geometry/launch bounds as k_gru_mfma; grid 512 (2 blocks/CU even).
// ---------------------------------------------------------------------------
template<int V>
__global__ __launch_bounds__(512, 4) void k_abl(
        const unsigned short* __restrict__ X,
        const unsigned short* __restrict__ Bf,
        float* __restrict__ Ys) {
    __shared__ char lds[66048];

    const int tid = threadIdx.x;
    const int lane = tid & 63;
    const int wv = tid >> 6;
    const int r31 = lane & 31;
    const int kg = lane >> 5;
    const long row0 = (long)blockIdx.x * 64;

    f32x16 acc[2][2];
#pragma unroll
    for (int i = 0; i < 2; i++)
#pragma unroll
        for (int j = 0; j < 2; j++) acc[i][j] = (f32x16)(0.0f);

    const char* pAl = (const char*)X + (row0 + r31) * 1024 + kg * 16;
#define STAGE_AB(HALF)                                                          \
    {                                                                           \
        _Pragma("unroll")                                                       \
        for (int jj = 0; jj < 4; jj++) {                                        \
            const int f = wv * 4 + jj;                                          \
            gload16(pAl + (f & 1) * 32768 + ((HALF) * 16 + (f >> 1)) * 32,      \
                    lds + f * 1024);                                            \
        }                                                                       \
    }

    const unsigned short* pB0 = Bf + (wv * 2 + 0) * 16384 + lane * 8;
    const unsigned short* pB1 = Bf + (wv * 2 + 1) * 16384 + lane * 8;

    // frag-0 constants for the "removed" paths
    short8 b0c = *(const short8*)(pB0);
    short8 b1c = *(const short8*)(pB1);

    STAGE_A_DUMMY:;
    STAGE_AB(0);
    __syncthreads();

#pragma unroll
    for (int k16l = 0; k16l < 16; k16l++) {
        short8 a0, a1, b0, b1;
        if (V < 2) {
            a0 = *(const short8*)(lds + (k16l * 2 + 0) * 1024 + lane * 16);
            a1 = *(const short8*)(lds + (k16l * 2 + 1) * 1024 + lane * 16);
        } else { a0 = b0c; a1 = b1c; }
        if (V == 0 || V == 2) {
            b0 = *(const short8*)(pB0 + k16l * 512);
            b1 = *(const short8*)(pB1 + k16l * 512);
        } else { b0 = b0c; b1 = b1c; }
        acc[0][0] = MFMA(a0, b0, acc[0][0]);
        acc[0][1] = MFMA(a0, b1, acc[0][1]);
        acc[1][0] = MFMA(a1, b0, acc[1][0]);
        acc[1][1] = MFMA(a1, b1, acc[1][1]);
    }

    __syncthreads();
    STAGE_AB(1);
    __syncthreads();
#undef STAGE_AB

#pragma unroll
    for (int k16l = 0; k16l < 16; k16l++) {
        const int k16g = 16 + k16l;
        short8 a0, a1, b0, b1;
        if (V < 2) {
            a0 = *(const short8*)(lds + (k16l * 2 + 0) * 1024 + lane * 16);
            a1 = *(const short8*)(lds + (k16l * 2 + 1) * 1024 + lane * 16);
        } else { a0 = b0c; a1 = b1c; }
        if (V == 0 || V == 2) {
            b0 = *(const short8*)(pB0 + k16g * 512);
            b1 = *(const short8*)(pB1 + k16g * 512);
        } else { b0 = b0c; b1 = b1c; }
        acc[0][0] = MFMA(a0, b0, acc[0][0]);
        acc[0][1] = MFMA(a0, b1, acc[0][1]);
        acc[1][0] = MFMA(a1, b0, acc[1][0]);
        acc[1][1] = MFMA(a1, b1, acc[1][1]);
    }

    // keep all 4 acc chains live (one element each keeps the MFMA chains)
    float4 o;
    o.x = acc[0][0][0]; o.y = acc[0][1][0]; o.z = acc[1][0][0]; o.w = acc[1][1][0];
    *(float4*)(Ys + ((long)blockIdx.x * 512 + tid) * 4) = o;
}

// ---------------------------------------------------------------------------
// Readout: out[g] += sigmoid(h@Wg.T+bg) * (h@Wp.T+bp). h from Y bf16.
// ---------------------------------------------------------------------------
__global__ __launch_bounds__(256) void k_readout(const unsigned short* __restrict__ Y,
                                                 const int* __restrict__ n2g,
                                                 const float* __restrict__ Wp,
                                                 const float* __restrict__ bp,
                                                 const float* __restrict__ Wg,
                                                 const float* __restrict__ bg,
                                                 float* __restrict__ out) {
    __shared__ float hs[32][132];
    __shared__ float Ws[64][129];
    int tid = threadIdx.x;
    long row0 = (long)blockIdx.x * 32;
    int rg = tid >> 5, cg = tid & 31;
    float acc[4][4];
#pragma unroll
    for (int r = 0; r < 4; r++)
#pragma unroll
        for (int c = 0; c < 4; c++) acc[r][c] = 0.f;

#pragma unroll
    for (int p = 0; p < 2; p++) {
        int e = p * 256 + tid;
        int r = e >> 4, c8 = e & 15;
        short8 v = *(const short8*)(Y + (row0 + r) * HID + c8 * 8);
#pragma unroll
        for (int j = 0; j < 8; j++) hs[r][c8 * 8 + j] = bf2f((unsigned short)v[j]);
    }
    for (int kc = 0; kc < 128; kc += 64) {
        __syncthreads();
#pragma unroll
        for (int p = 0; p < 8; p++) {
            int idx = p * 256 + tid;
            int j = idx >> 4, q = idx & 15;
            const float* Wsrc = (j < 64) ? Wp : Wg;
            float4 w = *(const float4*)&Wsrc[(j & 63) * HID + kc + q * 4];
            Ws[q * 4 + 0][j] = w.x;
            Ws[q * 4 + 1][j] = w.y;
            Ws[q * 4 + 2][j] = w.z;
            Ws[q * 4 + 3][j] = w.w;
        }
        __syncthreads();
#pragma unroll 8
        for (int k = 0; k < 64; k++) {
            float a[4], w[4];
#pragma unroll
            for (int r = 0; r < 4; r++) a[r] = hs[rg * 4 + r][kc + k];
#pragma unroll
            for (int c = 0; c < 4; c++) w[c] = Ws[k][cg + 32 * c];
#pragma unroll
            for (int r = 0; r < 4; r++)
#pragma unroll
                for (int c = 0; c < 4; c++) acc[r][c] += a[r] * w[c];
        }
    }
#pragma unroll
    for (int r = 0; r < 4; r++) {
        long row = row0 + rg * 4 + r;
        if (row < NN) {
            int g = n2g[row];
            float pv0 = acc[r][0] + bp[cg];
            float pv1 = acc[r][1] + bp[cg + 32];
            float gv0 = acc[r][2] + bg[cg];
            float gv1 = acc[r][3] + bg[cg + 32];
            atomicAdd(&out[g * EMB + cg],      pv0 * sigm(gv0));
            atomicAdd(&out[g * EMB + cg + 32], pv1 * sigm(gv1));
        }
    }
}

// ---------------------------------------------------------------------------
extern "C" void kernel_launch(void* const* d_in, const int* in_sizes, int n_in,
                              void* d_out, int out_size, void* d_ws, size_t ws_size,
                              hipStream_t stream) {
    const float* node_features = (const float*)d_in[0];
    const int*   edge_index    = (const int*)d_in[1];
    const int*   n2g           = (const int*)d_in[2];
    const float* W_msg         = (const float*)d_in[3];
    const float* b_msg         = (const float*)d_in[4];
    const float* W_ih          = (const float*)d_in[5];
    const float* W_hh          = (const float*)d_in[6];
    const float* b_ih          = (const float*)d_in[7];
    const float* b_hh          = (const float*)d_in[8];
    const float* W_proj        = (const float*)d_in[9];
    const float* b_proj        = (const float*)d_in[10];
    const float* W_gate        = (const float*)d_in[11];
    const float* b_gate        = (const float*)d_in[12];

    char* ws = (char*)d_ws;
    unsigned short* X    = (unsigned short*)(ws);                 // 102,498,304 B
    unsigned short* Y    = (unsigned short*)(ws + 102498304);     //  25,624,576 B
    unsigned short* Bf   = (unsigned short*)(ws + 128122880);     //     524,288 B
    float*          bbig = (float*)         (ws + 128647168);     //       2,048 B
    float*          Bdeg = (float*)         (ws + 128649216);     //       6,144 B
    int4*           degp = (int4*)          (ws + 128655360);     //   1,601,536 B
    int*            deg  = (int*)           (ws + 130256896);     //   1,200,000 B
    int*            csr  = (int*)           (ws + 131456896);     //  38,400,000 B
    float*          Ys   = (float*)         (ws + 169856896);     //   4,194,304 B -> ~174 MB

    float* out = (float*)d_out;

    hipMemsetAsync(out, 0, (size_t)NG * EMB * sizeof(float), stream);
    hipMemsetAsync(deg, 0, (size_t)3 * NN * sizeof(int), stream);

    k_init<<<dim3((NNP * HID) / 256), dim3(256), 0, stream>>>(node_features, Y);
    k_build_csr<<<dim3((3 * NE + 255) / 256), dim3(256), 0, stream>>>(edge_index, deg, csr);
    k_pack_deg<<<dim3(NNP / 256), dim3(256), 0, stream>>>(deg, degp);
    k_build_w<<<dim3(512), dim3(512), 0, stream>>>(W_msg, W_ih, W_hh, Bf);
    k_build_bias<<<dim3(1), dim3(512), 0, stream>>>(b_ih, b_hh, b_msg, W_ih, bbig, Bdeg);

    for (int step = 0; step < 4; step++) {
        k_agg<<<dim3(NN / 4), dim3(256), 0, stream>>>(Y, X, deg, csr);
        k_gru_mfma<<<dim3(NNP / 64), dim3(512), 0, stream>>>(X, Y, Y, Bf,
                                                             bbig, Bdeg, degp);
    }
    k_readout<<<dim3(NN / 32), dim3(256), 0, stream>>>(Y, n2g, W_proj, b_proj,
                                                       W_gate, b_gate, out);

    // ---- diagnostic ablations (scratch-only, do not affect d_out) ----
    k_abl<0><<<dim3(512), dim3(512), 0, stream>>>(X, Bf, Ys);
    k_abl<1><<<dim3(512), dim3(512), 0, stream>>>(X, Bf, Ys);
    k_abl<2><<<dim3(512), dim3(512), 0, stream>>>(X, Bf, Ys);
    k_abl<3><<<dim3(512), dim3(512), 0, stream>>>(X, Bf, Ys);
}